// Round 2
// baseline (1359.454 us; speedup 1.0000x reference)
//
#include <hip/hip_runtime.h>
#include <hip/hip_bf16.h>

// ---------------------------------------------------------------------------
// HypergraphConv x2 + PReLU + residual. R6: gather MLP + cache hints.
//   R5 profile: 4x gather_rows at 247us each = 75% of runtime; VALUBusy 12%,
//   HBM 48% -> latency-bound (1 outstanding row-load per wave, runtime-count
//   loop defeats unrolling).
//   R6: 4x manual unroll (4 loads in flight, 2 acc chains), nontemporal
//   loads for single-use streams (adj, residual), nontemporal stores for
//   outputs with no random re-read (h, final out). make_inv folded into
//   bucket_fill.
// GEMM: split-bf16 MFMA (A@W = Ahi@Whi + Ahi@Wlo + Alo@Whi), unchanged.
// ---------------------------------------------------------------------------

#define F_DIM 256
#define CAP 48          // padded adjacency slots per node; P(deg>=48)~1e-10
#define BW_SHIFT 9      // bucket width 512 nodes
#define CHUNK 2048      // edges per partition block

using bf16x8 = __attribute__((ext_vector_type(8))) short;
using f32x4  = __attribute__((ext_vector_type(4))) float;

__device__ __forceinline__ short f2bf(float f) {
    __hip_bfloat16 h = __float2bfloat16(f);
    return *reinterpret_cast<short*>(&h);
}
__device__ __forceinline__ float bf2f(short s) {
    return __uint_as_float(((unsigned)(unsigned short)s) << 16);
}

// ---- 1. bucket cursor init -------------------------------------------------
__global__ void init_cur_kernel(int* __restrict__ cur, int n, int buckcap) {
    int i = blockIdx.x * blockDim.x + threadIdx.x;
    if (i < n) cur[i] = i * buckcap;
}

// ---- 2. partition: edges -> bucket-grouped (node,other) pairs --------------
// grid (nchunks, 2): dir 0 keys=src (for adjS/degS), dir 1 keys=dst.
__global__ __launch_bounds__(256) void partition_kernel(
    const int* __restrict__ src, const int* __restrict__ dst,
    int2* __restrict__ part, int* __restrict__ cur,
    int nnz, int nb, int buckcap)
{
    __shared__ int lhist[256];
    __shared__ int lscan[256];
    __shared__ int gbase[256];
    __shared__ int sh_total;
    __shared__ int2 lstage[CHUNK];   // 16 KB

    const int tid = threadIdx.x;
    const int dir = blockIdx.y;
    const int base = blockIdx.x * CHUNK;
    const int* __restrict__ key = dir ? dst : src;
    const int* __restrict__ val = dir ? src : dst;

    lhist[tid] = 0;
    __syncthreads();

    int mykey[8], myval[8], myb[8], myr[8];
#pragma unroll
    for (int i = 0; i < 8; ++i) {
        int g = base + tid + i * 256;
        myb[i] = -1;
        if (g < nnz) {
            mykey[i] = key[g];
            myval[i] = val[g];
            myb[i] = mykey[i] >> BW_SHIFT;
            myr[i] = atomicAdd(&lhist[myb[i]], 1);   // LDS atomic: rank in block
        }
    }
    __syncthreads();

    // inclusive scan of per-bucket counts (Hillis-Steele over 256 bins)
    int v0 = lhist[tid];
    lscan[tid] = v0;
    __syncthreads();
    for (int off = 1; off < 256; off <<= 1) {
        int add = (tid >= off) ? lscan[tid - off] : 0;
        __syncthreads();
        lscan[tid] += add;
        __syncthreads();
    }
    int incl = lscan[tid];
    if (tid == 255) sh_total = incl;
    // reserve global space: one atomic per non-empty bucket per block
    if (tid < nb && v0 > 0) gbase[tid] = atomicAdd(&cur[dir * nb + tid], v0);
    __syncthreads();
    lscan[tid] = incl - v0;          // exclusive
    __syncthreads();

    // stage sorted-by-bucket in LDS
#pragma unroll
    for (int i = 0; i < 8; ++i)
        if (myb[i] >= 0)
            lstage[lscan[myb[i]] + myr[i]] = make_int2(mykey[i], myval[i]);
    __syncthreads();

    // write out bucket runs (consecutive k -> consecutive dest = coalesced)
    const int total = sh_total;
    for (int k = tid; k < total; k += 256) {
        int2 v = lstage[k];
        int b = v.x >> BW_SHIFT;
        int pos = gbase[b] + (k - lscan[b]);
        if (pos < (dir * nb + b + 1) * buckcap)   // overflow guard (never fires)
            part[pos] = v;
    }
}

// ---- 3. per-bucket fill: LDS per-node counters, L2-local adj writes --------
//         also emits deg[] and inverse-degree (Dinv/Binv) directly.
__global__ __launch_bounds__(256) void bucket_fill_kernel(
    const int2* __restrict__ part, const int* __restrict__ cur,
    int* __restrict__ adjS, int* __restrict__ adjD,
    int* __restrict__ degS, int* __restrict__ degD,
    float* __restrict__ Dinv, float* __restrict__ Binv,
    int M, int nb, int buckcap)
{
    __shared__ int lcnt[512];
    const int tid = threadIdx.x;
    const int b = blockIdx.x;
    const int dir = blockIdx.y;
    const int c = dir * nb + b;
    int* __restrict__ adj = dir ? adjD : adjS;
    int* __restrict__ deg = dir ? degD : degS;
    float* __restrict__ inv = dir ? Binv : Dinv;

    lcnt[tid] = 0;
    lcnt[tid + 256] = 0;
    __syncthreads();

    const int pbase = c * buckcap;
    const int cnt = min(cur[c] - pbase, buckcap);
    const int node0 = b << BW_SHIFT;
    for (int i = tid; i < cnt; i += 256) {
        int2 v = part[pbase + i];
        int r = atomicAdd(&lcnt[v.x - node0], 1);    // LDS atomic
        if (r < CAP) adj[(size_t)v.x * CAP + r] = v.y;
    }
    __syncthreads();
    for (int i = tid; i < 512; i += 256) {
        int node = node0 + i;
        if (node < M) {
            int d = min(lcnt[i], CAP);
            deg[node] = d;
            inv[node] = d > 0 ? 1.f / (float)d : 0.f;
        }
    }
}

// ---- 4. W prepack: f32 -> bf16 hi/lo MFMA B-fragment order -----------------
// frag blob (kt,nt): 64 lanes x 8; lane holds B[kt*32+(lane>>4)*8+j][nt*16+(lane&15)]
__global__ void prepack_w_kernel(const float* __restrict__ W,
                                 short* __restrict__ Whi, short* __restrict__ Wlo) {
    int lane = threadIdx.x;            // 64
    int nt = blockIdx.x;               // 16
    int kt = blockIdx.y;               // 8
    int col = nt * 16 + (lane & 15);
    int krow = kt * 32 + (lane >> 4) * 8;
    size_t o = ((size_t)(kt * 16 + nt) * 64 + lane) * 8;
#pragma unroll
    for (int j = 0; j < 8; ++j) {
        float w = W[(size_t)(krow + j) * 256 + col];
        short hi = f2bf(w);
        Whi[o + j] = hi;
        Wlo[o + j] = f2bf(w - bf2f(hi));
    }
}

// ---- 5. split-bf16 MFMA GEMM: C[M,256](f32) = A[M,256](f32) @ W ------------
// block 256 thr = 4 waves (2x2 of 64x64); tile 128(M) x 128(N); K-loop 8x32.
__global__ __launch_bounds__(256) void gemm_mfma_split(const float* __restrict__ A,
                                                       const short* __restrict__ Whi,
                                                       const short* __restrict__ Wlo,
                                                       float* __restrict__ C, int M) {
    __shared__ short AsHi[4][128][8];    // 8 KB
    __shared__ short AsLo[4][128][8];    // 8 KB
    const int tid = threadIdx.x;
    const int w = tid >> 6, lane = tid & 63;
    const int quad = lane >> 4, l16 = lane & 15;
    const int bm = blockIdx.x * 128;
    const int bn_t = blockIdx.y * 8;             // n-tile base (16-col tiles)
    const int wm = (w & 1) * 64;
    const int wnt = (w >> 1) * 4;

    f32x4 acc[4][4] = {};

    for (int kt = 0; kt < 8; ++kt) {
        __syncthreads();
        // stage A tile: 128 rows x 32 k, f32 -> bf16 hi/lo
#pragma unroll
        for (int i = 0; i < 2; ++i) {
            int idx = tid + i * 256;
            int row = idx >> 2, seg = idx & 3;
            int grow = bm + row; if (grow >= M) grow = M - 1;
            const float* ap = A + (size_t)grow * 256 + kt * 32 + seg * 8;
            float4 v0 = *(const float4*)ap;
            float4 v1 = *(const float4*)(ap + 4);
            float vv[8] = {v0.x, v0.y, v0.z, v0.w, v1.x, v1.y, v1.z, v1.w};
            union { short s[8]; int4 q; } uh, ul;
#pragma unroll
            for (int e = 0; e < 8; ++e) {
                short hi = f2bf(vv[e]);
                uh.s[e] = hi;
                ul.s[e] = f2bf(vv[e] - bf2f(hi));
            }
            *(int4*)&AsHi[seg][row][0] = uh.q;
            *(int4*)&AsLo[seg][row][0] = ul.q;
        }
        __syncthreads();

        bf16x8 ahi[4], alo[4];
#pragma unroll
        for (int i = 0; i < 4; ++i) {
            ahi[i] = *(const bf16x8*)&AsHi[quad][wm + i * 16 + l16][0];
            alo[i] = *(const bf16x8*)&AsLo[quad][wm + i * 16 + l16][0];
        }

#pragma unroll
        for (int j = 0; j < 4; ++j) {
            int nt = bn_t + wnt + j;
            size_t off = ((size_t)(kt * 16 + nt) * 64 + lane) * 8;
            bf16x8 bhi = *(const bf16x8*)(Whi + off);
            bf16x8 blo = *(const bf16x8*)(Wlo + off);
#pragma unroll
            for (int i = 0; i < 4; ++i) {
                acc[i][j] = __builtin_amdgcn_mfma_f32_16x16x32_bf16(ahi[i], bhi, acc[i][j], 0, 0, 0);
                acc[i][j] = __builtin_amdgcn_mfma_f32_16x16x32_bf16(ahi[i], blo, acc[i][j], 0, 0, 0);
                acc[i][j] = __builtin_amdgcn_mfma_f32_16x16x32_bf16(alo[i], bhi, acc[i][j], 0, 0, 0);
            }
        }
    }

    // epilogue: C[row][col] = acc (f32); row = wm + i*16 + quad*4 + r, col per tile
#pragma unroll
    for (int i = 0; i < 4; ++i) {
#pragma unroll
        for (int j = 0; j < 4; ++j) {
            int col = (bn_t + wnt + j) * 16 + l16;
            int row0 = bm + wm + i * 16 + quad * 4;
#pragma unroll
            for (int r = 0; r < 4; ++r) {
                int row = row0 + r;
                if (row < M) C[(size_t)row * 256 + col] = acc[i][j][r];
            }
        }
    }
}

// ---- 6. pull gather (f32): out[r] = f(scale[r]*sum_{j in adj[r]} src[j]) ---
// padded adjacency: row r lives at adj[r*CAP .. r*CAP+deg[r]).
// 4x unrolled neighbor loop -> 4 row-loads in flight per wave (MLP).
__global__ __launch_bounds__(256) void gather_rows_kernel(const float* __restrict__ src_mat,
                                                          float* __restrict__ out_mat,
                                                          const int* __restrict__ deg,
                                                          const int* __restrict__ adj,
                                                          const float* __restrict__ scale,
                                                          const float* __restrict__ bias,
                                                          const float* __restrict__ residual,
                                                          const float* __restrict__ alpha_p,
                                                          int n, int nt_out) {
    int wid = (blockIdx.x * blockDim.x + threadIdx.x) >> 6;
    int lane = threadIdx.x & 63;
    if (wid >= n) return;
    const int dcount = deg[wid];                      // <= CAP (48) < 64
    const int* arow = adj + (size_t)wid * CAP;
    int myidx = (lane < dcount) ? __builtin_nontemporal_load(arow + lane) : 0;

    const size_t lo = (size_t)lane * 4;
    float ax0 = 0.f, ay0 = 0.f, az0 = 0.f, aw0 = 0.f;
    float ax1 = 0.f, ay1 = 0.f, az1 = 0.f, aw1 = 0.f;

    int j = 0;
    for (; j + 4 <= dcount; j += 4) {
        int i0 = __shfl(myidx, j);
        int i1 = __shfl(myidx, j + 1);
        int i2 = __shfl(myidx, j + 2);
        int i3 = __shfl(myidx, j + 3);
        float4 v0 = *(const float4*)(src_mat + (size_t)i0 * F_DIM + lo);
        float4 v1 = *(const float4*)(src_mat + (size_t)i1 * F_DIM + lo);
        float4 v2 = *(const float4*)(src_mat + (size_t)i2 * F_DIM + lo);
        float4 v3 = *(const float4*)(src_mat + (size_t)i3 * F_DIM + lo);
        ax0 += v0.x; ay0 += v0.y; az0 += v0.z; aw0 += v0.w;
        ax1 += v1.x; ay1 += v1.y; az1 += v1.z; aw1 += v1.w;
        ax0 += v2.x; ay0 += v2.y; az0 += v2.z; aw0 += v2.w;
        ax1 += v3.x; ay1 += v3.y; az1 += v3.z; aw1 += v3.w;
    }
    for (; j < dcount; ++j) {
        int i0 = __shfl(myidx, j);
        float4 v0 = *(const float4*)(src_mat + (size_t)i0 * F_DIM + lo);
        ax0 += v0.x; ay0 += v0.y; az0 += v0.z; aw0 += v0.w;
    }

    float4 acc;
    acc.x = ax0 + ax1; acc.y = ay0 + ay1; acc.z = az0 + az1; acc.w = aw0 + aw1;

    float sc = scale[wid];
    acc.x *= sc; acc.y *= sc; acc.z *= sc; acc.w *= sc;
    if (bias) {
        float4 bb = ((const float4*)bias)[lane];
        acc.x += bb.x; acc.y += bb.y; acc.z += bb.z; acc.w += bb.w;
    }
    if (residual) {
        const float* rp = residual + (size_t)wid * F_DIM + lo;
        float4 xv;
        xv.x = __builtin_nontemporal_load(rp + 0);
        xv.y = __builtin_nontemporal_load(rp + 1);
        xv.z = __builtin_nontemporal_load(rp + 2);
        xv.w = __builtin_nontemporal_load(rp + 3);
        acc.x += xv.x; acc.y += xv.y; acc.z += xv.z; acc.w += xv.w;
    }
    if (alpha_p) {
        float al = alpha_p[0];
        acc.x = acc.x >= 0.f ? acc.x : al * acc.x;
        acc.y = acc.y >= 0.f ? acc.y : al * acc.y;
        acc.z = acc.z >= 0.f ? acc.z : al * acc.z;
        acc.w = acc.w >= 0.f ? acc.w : al * acc.w;
    }
    float* op = out_mat + (size_t)wid * F_DIM + lo;
    if (nt_out) {
        __builtin_nontemporal_store(acc.x, op + 0);
        __builtin_nontemporal_store(acc.y, op + 1);
        __builtin_nontemporal_store(acc.z, op + 2);
        __builtin_nontemporal_store(acc.w, op + 3);
    } else {
        *(float4*)op = acc;
    }
}

// ---------------------------------------------------------------------------
extern "C" void kernel_launch(void* const* d_in, const int* in_sizes, int n_in,
                              void* d_out, int out_size, void* d_ws, size_t ws_size,
                              hipStream_t stream) {
    const float* x   = (const float*)d_in[0];
    const int*   ei  = (const int*)d_in[1];
    const float* W1  = (const float*)d_in[2];
    const float* b1  = (const float*)d_in[3];
    const float* W2  = (const float*)d_in[4];
    const float* b2  = (const float*)d_in[5];
    const float* a   = (const float*)d_in[6];
    float* out = (float*)d_out;

    const int M   = in_sizes[0] / F_DIM;   // 100000
    const int nnz = in_sizes[1] / 2;       // 1600000
    const int* src = ei;
    const int* dst = ei + nnz;

    const int NB = (M + (1 << BW_SHIFT) - 1) >> BW_SHIFT;              // 196
    const int avg = (int)(((long long)nnz << BW_SHIFT) / M);           // ~8192
    const int BUCKCAP = avg + avg / 8 + 256;                           // ~9472 (+14 sigma)
    const int nchunks = (nnz + CHUNK - 1) / CHUNK;

    char* p = (char*)d_ws;
    const size_t nbuf = (size_t)M * F_DIM * sizeof(float);     // 102.4 MB
    const size_t wpk  = 8 * 16 * 64 * 8 * sizeof(short);       // 128 KB
    float* bufA = (float*)p;               p += nbuf;
    float* bufB = (float*)p;               p += nbuf;
    short* W1hi = (short*)p;               p += wpk;
    short* W1lo = (short*)p;               p += wpk;
    short* W2hi = (short*)p;               p += wpk;
    short* W2lo = (short*)p;               p += wpk;
    int* adjS   = (int*)p;                 p += (size_t)M * CAP * 4;   // 19.2 MB
    int* adjD   = (int*)p;                 p += (size_t)M * CAP * 4;
    int* degS   = (int*)p;                 p += (size_t)M * 4;
    int* degD   = (int*)p;                 p += (size_t)M * 4;
    float* Dinv = (float*)p;               p += (size_t)M * 4;
    float* Binv = (float*)p;               p += (size_t)M * 4;
    int* bucketCur = (int*)p;              p += ((size_t)2 * NB * 4 + 15) & ~15ull;

    // partition scratch aliases bufA: dead before the first GEMM writes bufA.
    // size = 2*NB*BUCKCAP*8 ~ 29.7 MB <= 102.4 MB.
    int2* part = (int2*)bufA;

    const dim3 blk(256);
    const dim3 gemm_grid((M + 127) / 128, 2);
    const int gather_blocks = (M + 3) / 4;

    // ---- adjacency build (zero per-edge global atomics) ----
    init_cur_kernel<<<(2 * NB + 255) / 256, blk, 0, stream>>>(bucketCur, 2 * NB, BUCKCAP);
    partition_kernel<<<dim3(nchunks, 2), blk, 0, stream>>>(src, dst, part, bucketCur,
                                                           nnz, NB, BUCKCAP);
    bucket_fill_kernel<<<dim3(NB, 2), blk, 0, stream>>>(part, bucketCur, adjS, adjD,
                                                        degS, degD, Dinv, Binv,
                                                        M, NB, BUCKCAP);

    // ---- weight prepack (hi/lo) ----
    prepack_w_kernel<<<dim3(16, 8), 64, 0, stream>>>(W1, W1hi, W1lo);
    prepack_w_kernel<<<dim3(16, 8), 64, 0, stream>>>(W2, W2hi, W2lo);

    // ---- conv1 ----
    gemm_mfma_split<<<gemm_grid, blk, 0, stream>>>(x, W1hi, W1lo, bufA, M);        // xt
    gather_rows_kernel<<<gather_blocks, blk, 0, stream>>>(bufA, bufB, degD, adjD,
                                                          Binv, nullptr, nullptr, nullptr, M, 0);  // m
    gather_rows_kernel<<<gather_blocks, blk, 0, stream>>>(bufB, bufA, degS, adjS,
                                                          Dinv, b1, nullptr, a, M, 1);             // h
    // ---- conv2 ----
    gemm_mfma_split<<<gemm_grid, blk, 0, stream>>>(bufA, W2hi, W2lo, bufB, M);     // xt2
    gather_rows_kernel<<<gather_blocks, blk, 0, stream>>>(bufB, bufA, degD, adjD,
                                                          Binv, nullptr, nullptr, nullptr, M, 0);  // m2
    gather_rows_kernel<<<gather_blocks, blk, 0, stream>>>(bufA, out, degS, adjS,
                                                          Dinv, b2, x, a, M, 1);                   // prelu(.+x)
}

// Round 3
// 916.053 us; speedup vs baseline: 1.4840x; 1.4840x over previous
//
#include <hip/hip_runtime.h>
#include <hip/hip_bf16.h>

// ---------------------------------------------------------------------------
// HypergraphConv x2 + PReLU + residual. R7: f16 gather intermediates.
//   R6 post-mortem: gather BW pinned at ~3.85 TB/s regardless of per-wave
//   ILP -> service-rate ceiling for random 1KB-row reads. Lever = bytes.
//   R7: xt and m stored as f16 (rows 512B). f16 (not bf16): rel err 2^-11,
//   keeps absmax budget. h and final out stay f32; split-bf16 GEMM chain
//   untouched. NT stores reverted (R6: +21MB HBM writes). Unroll reverted
//   (R6: neutral, +12 VGPR).
// GEMM: split-bf16 MFMA (A@W = Ahi@Whi + Ahi@Wlo + Alo@Whi), f16 C output.
// ---------------------------------------------------------------------------

#define F_DIM 256
#define CAP 48          // padded adjacency slots per node; P(deg>=48)~1e-10
#define BW_SHIFT 9      // bucket width 512 nodes
#define CHUNK 2048      // edges per partition block

using bf16x8 = __attribute__((ext_vector_type(8))) short;
using f32x4  = __attribute__((ext_vector_type(4))) float;
using half4  = __attribute__((ext_vector_type(4))) _Float16;

__device__ __forceinline__ short f2bf(float f) {
    __hip_bfloat16 h = __float2bfloat16(f);
    return *reinterpret_cast<short*>(&h);
}
__device__ __forceinline__ float bf2f(short s) {
    return __uint_as_float(((unsigned)(unsigned short)s) << 16);
}

// ---- 1. bucket cursor init -------------------------------------------------
__global__ void init_cur_kernel(int* __restrict__ cur, int n, int buckcap) {
    int i = blockIdx.x * blockDim.x + threadIdx.x;
    if (i < n) cur[i] = i * buckcap;
}

// ---- 2. partition: edges -> bucket-grouped (node,other) pairs --------------
// grid (nchunks, 2): dir 0 keys=src (for adjS/degS), dir 1 keys=dst.
__global__ __launch_bounds__(256) void partition_kernel(
    const int* __restrict__ src, const int* __restrict__ dst,
    int2* __restrict__ part, int* __restrict__ cur,
    int nnz, int nb, int buckcap)
{
    __shared__ int lhist[256];
    __shared__ int lscan[256];
    __shared__ int gbase[256];
    __shared__ int sh_total;
    __shared__ int2 lstage[CHUNK];   // 16 KB

    const int tid = threadIdx.x;
    const int dir = blockIdx.y;
    const int base = blockIdx.x * CHUNK;
    const int* __restrict__ key = dir ? dst : src;
    const int* __restrict__ val = dir ? src : dst;

    lhist[tid] = 0;
    __syncthreads();

    int mykey[8], myval[8], myb[8], myr[8];
#pragma unroll
    for (int i = 0; i < 8; ++i) {
        int g = base + tid + i * 256;
        myb[i] = -1;
        if (g < nnz) {
            mykey[i] = key[g];
            myval[i] = val[g];
            myb[i] = mykey[i] >> BW_SHIFT;
            myr[i] = atomicAdd(&lhist[myb[i]], 1);   // LDS atomic: rank in block
        }
    }
    __syncthreads();

    // inclusive scan of per-bucket counts (Hillis-Steele over 256 bins)
    int v0 = lhist[tid];
    lscan[tid] = v0;
    __syncthreads();
    for (int off = 1; off < 256; off <<= 1) {
        int add = (tid >= off) ? lscan[tid - off] : 0;
        __syncthreads();
        lscan[tid] += add;
        __syncthreads();
    }
    int incl = lscan[tid];
    if (tid == 255) sh_total = incl;
    // reserve global space: one atomic per non-empty bucket per block
    if (tid < nb && v0 > 0) gbase[tid] = atomicAdd(&cur[dir * nb + tid], v0);
    __syncthreads();
    lscan[tid] = incl - v0;          // exclusive
    __syncthreads();

    // stage sorted-by-bucket in LDS
#pragma unroll
    for (int i = 0; i < 8; ++i)
        if (myb[i] >= 0)
            lstage[lscan[myb[i]] + myr[i]] = make_int2(mykey[i], myval[i]);
    __syncthreads();

    // write out bucket runs (consecutive k -> consecutive dest = coalesced)
    const int total = sh_total;
    for (int k = tid; k < total; k += 256) {
        int2 v = lstage[k];
        int b = v.x >> BW_SHIFT;
        int pos = gbase[b] + (k - lscan[b]);
        if (pos < (dir * nb + b + 1) * buckcap)   // overflow guard (never fires)
            part[pos] = v;
    }
}

// ---- 3. per-bucket fill: LDS per-node counters, L2-local adj writes --------
//         also emits deg[] and inverse-degree (Dinv/Binv) directly.
__global__ __launch_bounds__(256) void bucket_fill_kernel(
    const int2* __restrict__ part, const int* __restrict__ cur,
    int* __restrict__ adjS, int* __restrict__ adjD,
    int* __restrict__ degS, int* __restrict__ degD,
    float* __restrict__ Dinv, float* __restrict__ Binv,
    int M, int nb, int buckcap)
{
    __shared__ int lcnt[512];
    const int tid = threadIdx.x;
    const int b = blockIdx.x;
    const int dir = blockIdx.y;
    const int c = dir * nb + b;
    int* __restrict__ adj = dir ? adjD : adjS;
    int* __restrict__ deg = dir ? degD : degS;
    float* __restrict__ inv = dir ? Binv : Dinv;

    lcnt[tid] = 0;
    lcnt[tid + 256] = 0;
    __syncthreads();

    const int pbase = c * buckcap;
    const int cnt = min(cur[c] - pbase, buckcap);
    const int node0 = b << BW_SHIFT;
    for (int i = tid; i < cnt; i += 256) {
        int2 v = part[pbase + i];
        int r = atomicAdd(&lcnt[v.x - node0], 1);    // LDS atomic
        if (r < CAP) adj[(size_t)v.x * CAP + r] = v.y;
    }
    __syncthreads();
    for (int i = tid; i < 512; i += 256) {
        int node = node0 + i;
        if (node < M) {
            int d = min(lcnt[i], CAP);
            deg[node] = d;
            inv[node] = d > 0 ? 1.f / (float)d : 0.f;
        }
    }
}

// ---- 4. W prepack: f32 -> bf16 hi/lo MFMA B-fragment order -----------------
// frag blob (kt,nt): 64 lanes x 8; lane holds B[kt*32+(lane>>4)*8+j][nt*16+(lane&15)]
__global__ void prepack_w_kernel(const float* __restrict__ W,
                                 short* __restrict__ Whi, short* __restrict__ Wlo) {
    int lane = threadIdx.x;            // 64
    int nt = blockIdx.x;               // 16
    int kt = blockIdx.y;               // 8
    int col = nt * 16 + (lane & 15);
    int krow = kt * 32 + (lane >> 4) * 8;
    size_t o = ((size_t)(kt * 16 + nt) * 64 + lane) * 8;
#pragma unroll
    for (int j = 0; j < 8; ++j) {
        float w = W[(size_t)(krow + j) * 256 + col];
        short hi = f2bf(w);
        Whi[o + j] = hi;
        Wlo[o + j] = f2bf(w - bf2f(hi));
    }
}

// ---- 5. split-bf16 MFMA GEMM: C[M,256](f16) = A[M,256](f32) @ W ------------
// block 256 thr = 4 waves (2x2 of 64x64); tile 128(M) x 128(N); K-loop 8x32.
__global__ __launch_bounds__(256) void gemm_mfma_split(const float* __restrict__ A,
                                                       const short* __restrict__ Whi,
                                                       const short* __restrict__ Wlo,
                                                       _Float16* __restrict__ C, int M) {
    __shared__ short AsHi[4][128][8];    // 8 KB
    __shared__ short AsLo[4][128][8];    // 8 KB
    const int tid = threadIdx.x;
    const int w = tid >> 6, lane = tid & 63;
    const int quad = lane >> 4, l16 = lane & 15;
    const int bm = blockIdx.x * 128;
    const int bn_t = blockIdx.y * 8;             // n-tile base (16-col tiles)
    const int wm = (w & 1) * 64;
    const int wnt = (w >> 1) * 4;

    f32x4 acc[4][4] = {};

    for (int kt = 0; kt < 8; ++kt) {
        __syncthreads();
        // stage A tile: 128 rows x 32 k, f32 -> bf16 hi/lo
#pragma unroll
        for (int i = 0; i < 2; ++i) {
            int idx = tid + i * 256;
            int row = idx >> 2, seg = idx & 3;
            int grow = bm + row; if (grow >= M) grow = M - 1;
            const float* ap = A + (size_t)grow * 256 + kt * 32 + seg * 8;
            float4 v0 = *(const float4*)ap;
            float4 v1 = *(const float4*)(ap + 4);
            float vv[8] = {v0.x, v0.y, v0.z, v0.w, v1.x, v1.y, v1.z, v1.w};
            union { short s[8]; int4 q; } uh, ul;
#pragma unroll
            for (int e = 0; e < 8; ++e) {
                short hi = f2bf(vv[e]);
                uh.s[e] = hi;
                ul.s[e] = f2bf(vv[e] - bf2f(hi));
            }
            *(int4*)&AsHi[seg][row][0] = uh.q;
            *(int4*)&AsLo[seg][row][0] = ul.q;
        }
        __syncthreads();

        bf16x8 ahi[4], alo[4];
#pragma unroll
        for (int i = 0; i < 4; ++i) {
            ahi[i] = *(const bf16x8*)&AsHi[quad][wm + i * 16 + l16][0];
            alo[i] = *(const bf16x8*)&AsLo[quad][wm + i * 16 + l16][0];
        }

#pragma unroll
        for (int j = 0; j < 4; ++j) {
            int nt = bn_t + wnt + j;
            size_t off = ((size_t)(kt * 16 + nt) * 64 + lane) * 8;
            bf16x8 bhi = *(const bf16x8*)(Whi + off);
            bf16x8 blo = *(const bf16x8*)(Wlo + off);
#pragma unroll
            for (int i = 0; i < 4; ++i) {
                acc[i][j] = __builtin_amdgcn_mfma_f32_16x16x32_bf16(ahi[i], bhi, acc[i][j], 0, 0, 0);
                acc[i][j] = __builtin_amdgcn_mfma_f32_16x16x32_bf16(ahi[i], blo, acc[i][j], 0, 0, 0);
                acc[i][j] = __builtin_amdgcn_mfma_f32_16x16x32_bf16(alo[i], bhi, acc[i][j], 0, 0, 0);
            }
        }
    }

    // epilogue: C[row][col] = (f16)acc; row = wm + i*16 + quad*4 + r, col per tile
#pragma unroll
    for (int i = 0; i < 4; ++i) {
#pragma unroll
        for (int j = 0; j < 4; ++j) {
            int col = (bn_t + wnt + j) * 16 + l16;
            int row0 = bm + wm + i * 16 + quad * 4;
#pragma unroll
            for (int r = 0; r < 4; ++r) {
                int row = row0 + r;
                if (row < M) C[(size_t)row * 256 + col] = (_Float16)acc[i][j][r];
            }
        }
    }
}

// ---- 6. pull gather: out[r] = f(scale[r]*sum_{j in adj[r]} src[j]) ---------
// src rows are f16 (512B). padded adjacency: row r at adj[r*CAP .. +deg[r]).
// OUT_F16=1 -> f16 output (xt->m hop); OUT_F16=0 -> f32 output (m->node hop).
template <int OUT_F16>
__global__ __launch_bounds__(256) void gather_rows_kernel(const _Float16* __restrict__ src_mat,
                                                          void* __restrict__ out_mat,
                                                          const int* __restrict__ deg,
                                                          const int* __restrict__ adj,
                                                          const float* __restrict__ scale,
                                                          const float* __restrict__ bias,
                                                          const float* __restrict__ residual,
                                                          const float* __restrict__ alpha_p,
                                                          int n) {
    int wid = (blockIdx.x * blockDim.x + threadIdx.x) >> 6;
    int lane = threadIdx.x & 63;
    if (wid >= n) return;
    const int dcount = deg[wid];                      // <= CAP (48) < 64
    const int* arow = adj + (size_t)wid * CAP;
    int myidx = (lane < dcount) ? __builtin_nontemporal_load(arow + lane) : 0;

    const size_t lo = (size_t)lane * 4;               // 4 f16 elems = 8B per lane
    float a0 = 0.f, a1 = 0.f, a2 = 0.f, a3 = 0.f;

    for (int j = 0; j < dcount; ++j) {
        int idx = __shfl(myidx, j);
        half4 v = *(const half4*)(src_mat + (size_t)idx * F_DIM + lo);
        a0 += (float)v.x; a1 += (float)v.y; a2 += (float)v.z; a3 += (float)v.w;
    }

    float sc = scale[wid];
    a0 *= sc; a1 *= sc; a2 *= sc; a3 *= sc;
    if (bias) {
        float4 bb = ((const float4*)bias)[lane];
        a0 += bb.x; a1 += bb.y; a2 += bb.z; a3 += bb.w;
    }
    if (residual) {
        const float* rp = residual + (size_t)wid * F_DIM + lo;
        float4 xv;
        xv.x = __builtin_nontemporal_load(rp + 0);
        xv.y = __builtin_nontemporal_load(rp + 1);
        xv.z = __builtin_nontemporal_load(rp + 2);
        xv.w = __builtin_nontemporal_load(rp + 3);
        a0 += xv.x; a1 += xv.y; a2 += xv.z; a3 += xv.w;
    }
    if (alpha_p) {
        float al = alpha_p[0];
        a0 = a0 >= 0.f ? a0 : al * a0;
        a1 = a1 >= 0.f ? a1 : al * a1;
        a2 = a2 >= 0.f ? a2 : al * a2;
        a3 = a3 >= 0.f ? a3 : al * a3;
    }
    if (OUT_F16) {
        half4 o;
        o.x = (_Float16)a0; o.y = (_Float16)a1; o.z = (_Float16)a2; o.w = (_Float16)a3;
        *(half4*)((_Float16*)out_mat + (size_t)wid * F_DIM + lo) = o;
    } else {
        float4 o = make_float4(a0, a1, a2, a3);
        *(float4*)((float*)out_mat + (size_t)wid * F_DIM + lo) = o;
    }
}

// ---------------------------------------------------------------------------
extern "C" void kernel_launch(void* const* d_in, const int* in_sizes, int n_in,
                              void* d_out, int out_size, void* d_ws, size_t ws_size,
                              hipStream_t stream) {
    const float* x   = (const float*)d_in[0];
    const int*   ei  = (const int*)d_in[1];
    const float* W1  = (const float*)d_in[2];
    const float* b1  = (const float*)d_in[3];
    const float* W2  = (const float*)d_in[4];
    const float* b2  = (const float*)d_in[5];
    const float* a   = (const float*)d_in[6];
    float* out = (float*)d_out;

    const int M   = in_sizes[0] / F_DIM;   // 100000
    const int nnz = in_sizes[1] / 2;       // 1600000
    const int* src = ei;
    const int* dst = ei + nnz;

    const int NB = (M + (1 << BW_SHIFT) - 1) >> BW_SHIFT;              // 196
    const int avg = (int)(((long long)nnz << BW_SHIFT) / M);           // ~8192
    const int BUCKCAP = avg + avg / 8 + 256;                           // ~9472 (+14 sigma)
    const int nchunks = (nnz + CHUNK - 1) / CHUNK;

    char* p = (char*)d_ws;
    const size_t nbuf   = (size_t)M * F_DIM * sizeof(float);      // 102.4 MB
    const size_t nbuf16 = (size_t)M * F_DIM * sizeof(_Float16);   // 51.2 MB
    const size_t wpk    = 8 * 16 * 64 * 8 * sizeof(short);        // 128 KB
    float*    bufH  = (float*)p;           p += nbuf;     // h (f32); part aliases
    _Float16* bufXT = (_Float16*)p;        p += nbuf16;   // xt (f16)
    _Float16* bufM  = (_Float16*)p;        p += nbuf16;   // m  (f16)
    short* W1hi = (short*)p;               p += wpk;
    short* W1lo = (short*)p;               p += wpk;
    short* W2hi = (short*)p;               p += wpk;
    short* W2lo = (short*)p;               p += wpk;
    int* adjS   = (int*)p;                 p += (size_t)M * CAP * 4;   // 19.2 MB
    int* adjD   = (int*)p;                 p += (size_t)M * CAP * 4;
    int* degS   = (int*)p;                 p += (size_t)M * 4;
    int* degD   = (int*)p;                 p += (size_t)M * 4;
    float* Dinv = (float*)p;               p += (size_t)M * 4;
    float* Binv = (float*)p;               p += (size_t)M * 4;
    int* bucketCur = (int*)p;              p += ((size_t)2 * NB * 4 + 15) & ~15ull;

    // partition scratch aliases bufH: dead before g2 writes bufH.
    // size = 2*NB*BUCKCAP*8 ~ 29.7 MB <= 102.4 MB.
    int2* part = (int2*)bufH;

    const dim3 blk(256);
    const dim3 gemm_grid((M + 127) / 128, 2);
    const int gather_blocks = (M + 3) / 4;

    // ---- adjacency build (zero per-edge global atomics) ----
    init_cur_kernel<<<(2 * NB + 255) / 256, blk, 0, stream>>>(bucketCur, 2 * NB, BUCKCAP);
    partition_kernel<<<dim3(nchunks, 2), blk, 0, stream>>>(src, dst, part, bucketCur,
                                                           nnz, NB, BUCKCAP);
    bucket_fill_kernel<<<dim3(NB, 2), blk, 0, stream>>>(part, bucketCur, adjS, adjD,
                                                        degS, degD, Dinv, Binv,
                                                        M, NB, BUCKCAP);

    // ---- weight prepack (hi/lo) ----
    prepack_w_kernel<<<dim3(16, 8), 64, 0, stream>>>(W1, W1hi, W1lo);
    prepack_w_kernel<<<dim3(16, 8), 64, 0, stream>>>(W2, W2hi, W2lo);

    // ---- conv1 ----
    gemm_mfma_split<<<gemm_grid, blk, 0, stream>>>(x, W1hi, W1lo, bufXT, M);       // xt (f16)
    gather_rows_kernel<1><<<gather_blocks, blk, 0, stream>>>(bufXT, bufM, degD, adjD,
                                                             Binv, nullptr, nullptr, nullptr, M); // m (f16)
    gather_rows_kernel<0><<<gather_blocks, blk, 0, stream>>>(bufM, bufH, degS, adjS,
                                                             Dinv, b1, nullptr, a, M);            // h (f32)
    // ---- conv2 ----
    gemm_mfma_split<<<gemm_grid, blk, 0, stream>>>(bufH, W2hi, W2lo, bufXT, M);    // xt2 (f16)
    gather_rows_kernel<1><<<gather_blocks, blk, 0, stream>>>(bufXT, bufM, degD, adjD,
                                                             Binv, nullptr, nullptr, nullptr, M); // m2 (f16)
    gather_rows_kernel<0><<<gather_blocks, blk, 0, stream>>>(bufM, out, degS, adjS,
                                                             Dinv, b2, x, a, M);                  // prelu(.+x)
}